// Round 4
// baseline (63.251 us; speedup 1.0000x reference)
//
#include <hip/hip_runtime.h>
#include <math.h>

// One WAVE (64 lanes) per walker; block = 256 = 4 independent walkers.
// Per wave: h rows global->reg (read once, reused for output), dot via
// register W + halving butterfly, wave-private LDS for M/anti/dist,
// 8-lane per-spin dets, out stored from register-held h.

__global__ __launch_bounds__(256, 4)
void orbital_cof_kernel(const float* __restrict__ h_g,   // (B,16,256)
                        const float* __restrict__ r_g,   // (B,16,4,3)
                        const float* __restrict__ W_g,   // (2,256,8)
                        const float* __restrict__ b_g,   // (2,8)
                        const float* __restrict__ dec_g, // (2,4,8)
                        const float* __restrict__ pi_g,  // (2,4,8)
                        float* __restrict__ out,         // (2,B,8,256)
                        int nb)
{
    __shared__ float dist_s[4][64];   // wave-private [s*32+n*4+i]
    __shared__ float Msw[4][8][8];    // wave-private, reused per spin
    __shared__ float anti_s[4][8];    // wave-private, reused per spin

    const int t = threadIdx.x;
    const int wave = t >> 6;
    const int lane = t & 63;
    const int b = blockIdx.x * 4 + wave;
    const bool valid = b < nb;

    // ---- distances: lane = s*32+n*4+i matches r flat layout ----
    if (valid) {
        const float* rp = r_g + (size_t)b * 192 + lane * 3;
        float x = rp[0], y = rp[1], z = rp[2];
        dist_s[wave][lane] = sqrtf(x * x + y * y + z * z);
    }
    __syncthreads();

    for (int s = 0; s < 2; ++s) {
        float4 hv[8];                 // this spin's h rows, lane's d-slice
        if (valid) {
            const float* hb = h_g + (size_t)b * 4096 + s * 2048 + lane * 4;
#pragma unroll
            for (int n = 0; n < 8; ++n)
                hv[n] = *(const float4*)(hb + n * 256);

#pragma unroll
            for (int kh = 0; kh < 2; ++kh) {
                // W regs: lane covers d0=4*lane..+4, k=kh*4..+4 (L1/L2-hot)
                float wv[4][4];
                const float* wp = W_g + s * 2048 + lane * 32 + kh * 4;
#pragma unroll
                for (int dd = 0; dd < 4; ++dd) {
                    float4 w = *(const float4*)(wp + dd * 8);
                    wv[dd][0] = w.x; wv[dd][1] = w.y; wv[dd][2] = w.z; wv[dd][3] = w.w;
                }
                // partials: v[n*4+kl] over lane's 4 d
                float v[32];
#pragma unroll
                for (int n = 0; n < 8; ++n) {
#pragma unroll
                    for (int kl = 0; kl < 4; ++kl) {
                        float acc = hv[n].x * wv[0][kl];
                        acc = fmaf(hv[n].y, wv[1][kl], acc);
                        acc = fmaf(hv[n].z, wv[2][kl], acc);
                        acc = fmaf(hv[n].w, wv[3][kl], acc);
                        v[n * 4 + kl] = acc;
                    }
                }
                // halving butterfly over 64 lanes: even lane 2m ends with sum m
#pragma unroll
                for (int i = 0; i < 16; ++i) {
                    float send = (lane & 32) ? v[i] : v[i + 16];
                    float recv = __shfl_xor(send, 32);
                    v[i] = ((lane & 32) ? v[i + 16] : v[i]) + recv;
                }
#pragma unroll
                for (int i = 0; i < 8; ++i) {
                    float send = (lane & 16) ? v[i] : v[i + 8];
                    float recv = __shfl_xor(send, 16);
                    v[i] = ((lane & 16) ? v[i + 8] : v[i]) + recv;
                }
#pragma unroll
                for (int i = 0; i < 4; ++i) {
                    float send = (lane & 8) ? v[i] : v[i + 4];
                    float recv = __shfl_xor(send, 8);
                    v[i] = ((lane & 8) ? v[i + 4] : v[i]) + recv;
                }
#pragma unroll
                for (int i = 0; i < 2; ++i) {
                    float send = (lane & 4) ? v[i] : v[i + 2];
                    float recv = __shfl_xor(send, 4);
                    v[i] = ((lane & 4) ? v[i + 2] : v[i]) + recv;
                }
                {
                    float send = (lane & 2) ? v[0] : v[1];
                    float recv = __shfl_xor(send, 2);
                    v[0] = ((lane & 2) ? v[1] : v[0]) + recv;
                }
                float tot = v[0] + __shfl_xor(v[0], 1);

                // env + bias -> M (even lanes hold (n,kl) = lane>>1)
                if ((lane & 1) == 0) {
                    int idx = lane >> 1;
                    int n = idx >> 2;
                    int k = kh * 4 + (idx & 3);
                    float lin = tot + b_g[s * 8 + k];
                    float env = 0.f;
#pragma unroll
                    for (int i = 0; i < 4; ++i) {
                        float dd2 = dist_s[wave][s * 32 + n * 4 + i];
                        env = fmaf(pi_g[s * 32 + i * 8 + k],
                                   __expf(-dd2 * dec_g[s * 32 + i * 8 + k]), env);
                    }
                    Msw[wave][n][k] = lin * env;
                }
            }
        }
        __syncthreads();

        // ---- 8 cofactor dets for this spin (7x7, partial pivoting) ----
        if (valid && lane < 8) {
            int n = lane;
            float a[7][7];
#pragma unroll
            for (int i = 0; i < 7; ++i) {
                int src = i + (i >= n);   // skip row n
#pragma unroll
                for (int j = 0; j < 7; ++j) a[i][j] = Msw[wave][src][j + 1]; // skip col 0
            }
            float det = 1.f;
#pragma unroll
            for (int kk = 0; kk < 7; ++kk) {
#pragma unroll
                for (int i = kk + 1; i < 7; ++i) {
                    bool sw = fabsf(a[i][kk]) > fabsf(a[kk][kk]);
#pragma unroll
                    for (int j = kk; j < 7; ++j) {
                        float tk = a[kk][j], ti = a[i][j];
                        a[kk][j] = sw ? ti : tk;
                        a[i][j]  = sw ? tk : ti;
                    }
                    det = sw ? -det : det;
                }
                float piv = a[kk][kk];
                det *= piv;
                float rp = (piv != 0.f) ? (1.f / piv) : 0.f;
#pragma unroll
                for (int i = kk + 1; i < 7; ++i) {
                    float f = a[i][kk] * rp;
#pragma unroll
                    for (int j = kk + 1; j < 7; ++j) a[i][j] = fmaf(-f, a[kk][j], a[i][j]);
                }
            }
            float sgn = (n & 1) ? -1.f : 1.f;
            anti_s[wave][n] = Msw[wave][n][0] * sgn * det;
        }
        __syncthreads();

        // ---- out = h * anti from register-held h (no re-read) ----
        if (valid) {
            float* ob = out + (size_t)s * (size_t)nb * 2048 + (size_t)b * 2048 + lane * 4;
#pragma unroll
            for (int n = 0; n < 8; ++n) {
                float aa = anti_s[wave][n];
                float4 hx = hv[n];
                float4 o = make_float4(hx.x * aa, hx.y * aa, hx.z * aa, hx.w * aa);
                *(float4*)(ob + n * 256) = o;
            }
        }
        __syncthreads();   // protect Msw/anti reuse before next spin's writes
    }
}

extern "C" void kernel_launch(void* const* d_in, const int* in_sizes, int n_in,
                              void* d_out, int out_size, void* d_ws, size_t ws_size,
                              hipStream_t stream) {
    int nb = in_sizes[0] / 4096;      // B = elems / (S*N*D)
    const float* h_g   = (const float*)d_in[0];
    const float* r_g   = (const float*)d_in[1];
    const float* W_g   = (const float*)d_in[2];
    const float* b_g   = (const float*)d_in[3];
    const float* dec_g = (const float*)d_in[4];
    const float* pi_g  = (const float*)d_in[5];
    int grid = (nb + 3) / 4;
    orbital_cof_kernel<<<dim3(grid), dim3(256), 0, stream>>>(
        h_g, r_g, W_g, b_g, dec_g, pi_g, (float*)d_out, nb);
}